// Round 1
// baseline (1789.983 us; speedup 1.0000x reference)
//
// PatchedTransformer on MI355X — round 1: correct-first full-model bf16 MFMA pipeline.
//
// Design notes:
//  - Residual stream h kept fp32 (B, SPAD=1088, D). Rows s>=1026 zeroed (junk-safe).
//  - All GEMMs: 128x128 tile, BK=32, mfma_f32_16x16x32_bf16, global_load_lds(16B)
//    staging for both A (activations bf16, (M,K)) and Bt (weights bf16 transposed (N,K)).
//  - Weights fp32 -> bf16 + transpose per layer into a rotating 32MB slab (saves ws).
//  - Attention: flash-style, 64-q block x 17 k-tiles of 64; scores in fp32 with
//    graph_bias gather (spd_emb column in LDS) and the reference's q-row -1e9 mask added
//    in fp32 (replicates fp32 absorption -> uniform softmax on masked rows).
//    P goes through padded LDS (stride 80) to convert C-layout -> A-layout; V is
//    pre-transposed to (B,H,DH,SPAD).
//  - Mask semantics: valid = q < tml[b] + 2 (glen=1).
#include <hip/hip_runtime.h>

#define DMODEL 1024
#define DFF    4096
#define NHEAD  16
#define DHEAD  64
#define LTOK   1024
#define SEQ    1026
#define SPAD   1088
#define MPAD   2176
#define NVOC   5000
#define NVOCP  5120
#define MOUT   2050

typedef float  floatx4 __attribute__((ext_vector_type(4)));
typedef __bf16 bf16x8  __attribute__((ext_vector_type(8)));

__device__ __forceinline__ unsigned short f2b(float f) {
  unsigned int u = __builtin_bit_cast(unsigned int, f);
  u += 0x7FFFu + ((u >> 16) & 1u);          // RNE
  return (unsigned short)(u >> 16);
}
__device__ __forceinline__ float b2f(unsigned short v) {
  return __builtin_bit_cast(float, ((unsigned int)v) << 16);
}
__device__ __forceinline__ void gl2lds16(const void* g, void* l) {
  __builtin_amdgcn_global_load_lds((const __attribute__((address_space(1))) void*)g,
                                   (__attribute__((address_space(3))) void*)l, 16, 0, 0);
}
__device__ __forceinline__ floatx4 mfma16(bf16x8 a, bf16x8 b, floatx4 c) {
  return __builtin_amdgcn_mfma_f32_16x16x32_bf16(a, b, c, 0, 0, 0);
}

// ---------------- fp32 -> bf16 flat convert ----------------
__global__ __launch_bounds__(256) void f2b_kernel(const float* __restrict__ s,
                                                  unsigned short* __restrict__ d, int n) {
  int i = (blockIdx.x * 256 + threadIdx.x) * 4;
  if (i >= n) return;
  float4 v = *(const float4*)(s + i);
  ushort4 o; o.x = f2b(v.x); o.y = f2b(v.y); o.z = f2b(v.z); o.w = f2b(v.w);
  *(ushort4*)(d + i) = o;
}

// ------------- fp32 (R,C) -> bf16 transposed (C,R) -------------
__global__ __launch_bounds__(256) void transconv_kernel(
    const float* __restrict__ p0, const float* __restrict__ p1,
    const float* __restrict__ p2, const float* __restrict__ p3,
    unsigned short* __restrict__ dst, long dstZ, int R, int C) {
  const float* src = (blockIdx.z == 0) ? p0 : (blockIdx.z == 1) ? p1 : (blockIdx.z == 2) ? p2 : p3;
  dst += dstZ * blockIdx.z;
  __shared__ float T[64][68];
  const int r0 = blockIdx.y * 64, c0 = blockIdx.x * 64;
  const int tr = threadIdx.x >> 4, tc = threadIdx.x & 15;
#pragma unroll
  for (int it = 0; it < 4; it++) {
    int rl = tr + it * 16;
    int cg = c0 + tc * 4;
    float4 v = {0.f, 0.f, 0.f, 0.f};
    if (cg < C) v = *(const float4*)(src + (size_t)(r0 + rl) * C + cg);
    T[rl][tc * 4 + 0] = v.x; T[rl][tc * 4 + 1] = v.y;
    T[rl][tc * 4 + 2] = v.z; T[rl][tc * 4 + 3] = v.w;
  }
  __syncthreads();
#pragma unroll
  for (int it = 0; it < 4; it++) {
    int ol = tr + it * 16;
    int oc = c0 + ol;
    if (oc < C) {
      ushort4 o;
      o.x = f2b(T[tc * 4 + 0][ol]); o.y = f2b(T[tc * 4 + 1][ol]);
      o.z = f2b(T[tc * 4 + 2][ol]); o.w = f2b(T[tc * 4 + 3][ol]);
      *(ushort4*)(dst + (size_t)oc * R + r0 + tc * 4) = o;
    }
  }
}

// ---------------- embeddings / h assembly ----------------
__global__ __launch_bounds__(256) void build_h_kernel(
    float* __restrict__ h, const float* __restrict__ gf, const float* __restrict__ sos,
    const float* __restrict__ nodeE, const float* __restrict__ typeE,
    const float* __restrict__ posE, const int* __restrict__ sub) {
  const int s = blockIdx.x, b = blockIdx.y;
  const int c = threadIdx.x * 4;
  float* o = h + ((size_t)(b * SPAD + s)) * DMODEL + c;
  if (s >= SEQ) { o[0] = 0.f; o[1] = 0.f; o[2] = 0.f; o[3] = 0.f; return; }
  float4 p = *(const float4*)(posE + (size_t)s * DMODEL + c);
  if (s == 0) {
    float4 g = *(const float4*)(gf + (size_t)b * DMODEL + c);
    float4 t = *(const float4*)(typeE + DMODEL + c);
    o[0] = g.x + t.x + p.x; o[1] = g.y + t.y + p.y;
    o[2] = g.z + t.z + p.z; o[3] = g.w + t.w + p.w;
  } else {
    float4 t = *(const float4*)(typeE + c);
    int nid = (s == 1) ? 0 : sub[b * LTOK + s - 2];
    float4 ne = *(const float4*)(nodeE + (size_t)nid * DMODEL + c);
    if (s == 1) {
      float4 ss = *(const float4*)(sos + c);
      o[0] = ss.x + ne.x + t.x + p.x; o[1] = ss.y + ne.y + t.y + p.y;
      o[2] = ss.z + ne.z + t.z + p.z; o[3] = ss.w + ne.w + t.w + p.w;
    } else {  // adds on top of proj-GEMM output already in h
      o[0] += ne.x + t.x + p.x; o[1] += ne.y + t.y + p.y;
      o[2] += ne.z + t.z + p.z; o[3] += ne.w + t.w + p.w;
    }
  }
}

// ---------------- RMSNorm (fp32 in, bf16 out) ----------------
__global__ __launch_bounds__(256) void rmsnorm_kernel(const float* __restrict__ h,
                                                      const float* __restrict__ w,
                                                      unsigned short* __restrict__ out,
                                                      int final_mode) {
  const int r = blockIdx.x;
  int srow = r;
  if (final_mode) {
    if (r >= MOUT) {
      ushort4 z = {0, 0, 0, 0};
      *(ushort4*)(out + (size_t)r * DMODEL + threadIdx.x * 4) = z;
      return;
    }
    int b = r / 1025;
    srow = b * SPAD + 1 + (r - b * 1025);
  }
  float4 x = *(const float4*)(h + (size_t)srow * DMODEL + threadIdx.x * 4);
  float ss = x.x * x.x + x.y * x.y + x.z * x.z + x.w * x.w;
#pragma unroll
  for (int off = 32; off > 0; off >>= 1) ss += __shfl_down(ss, off);
  __shared__ float red[4];
  if ((threadIdx.x & 63) == 0) red[threadIdx.x >> 6] = ss;
  __syncthreads();
  float rs = rsqrtf((red[0] + red[1] + red[2] + red[3]) * (1.f / 1024.f) + 1e-6f);
  float4 ww = *(const float4*)(w + threadIdx.x * 4);
  ushort4 o;
  o.x = f2b(x.x * rs * ww.x); o.y = f2b(x.y * rs * ww.y);
  o.z = f2b(x.z * rs * ww.z); o.w = f2b(x.w * rs * ww.w);
  *(ushort4*)(out + (size_t)r * DMODEL + threadIdx.x * 4) = o;
}

// ---------------- V transpose: (B,SPAD,D) head slice -> (B,H,DH,SPAD) ----------------
__global__ __launch_bounds__(256) void vtrans_kernel(const unsigned short* __restrict__ v,
                                                     unsigned short* __restrict__ vt) {
  const int st = blockIdx.x, hh = blockIdx.y, b = blockIdx.z;
  __shared__ unsigned short T[64][72];
  const int tr = threadIdx.x >> 4, tc = threadIdx.x & 15;
#pragma unroll
  for (int it = 0; it < 4; it++) {
    int r = tr + it * 16;
    ushort4 val = *(const ushort4*)(v + ((size_t)(b * SPAD + st * 64 + r)) * DMODEL + hh * DHEAD + tc * 4);
    T[r][tc * 4 + 0] = val.x; T[r][tc * 4 + 1] = val.y;
    T[r][tc * 4 + 2] = val.z; T[r][tc * 4 + 3] = val.w;
  }
  __syncthreads();
#pragma unroll
  for (int it = 0; it < 4; it++) {
    int d = tr + it * 16;
    ushort4 o;
    o.x = T[tc * 4 + 0][d]; o.y = T[tc * 4 + 1][d];
    o.z = T[tc * 4 + 2][d]; o.w = T[tc * 4 + 3][d];
    *(ushort4*)(vt + (((size_t)(b * NHEAD + hh)) * DHEAD + d) * SPAD + st * 64 + tc * 4) = o;
  }
}

// ---------------- flash attention w/ graph bias + q-row mask ----------------
#define PST 80  // padded LDS row stride (ushorts): 4-way bank aliasing only
__global__ __launch_bounds__(256) void attn_kernel(
    const unsigned short* __restrict__ qb, const unsigned short* __restrict__ kb,
    const unsigned short* __restrict__ vt, unsigned short* __restrict__ attb,
    const float* __restrict__ spdE, const int* __restrict__ spd,
    const int* __restrict__ tml) {
  const int qt = blockIdx.x, hh = blockIdx.y, bb = blockIdx.z;
  const int tid = threadIdx.x;
  const int w = tid >> 6, lane = tid & 63;
  const int quad = lane >> 4, l16 = lane & 15;

  __shared__ unsigned short Qs[64 * PST];
  __shared__ unsigned short Ks[64 * PST];
  __shared__ unsigned short Vts[64 * PST];
  __shared__ unsigned short Ps[4 * 16 * PST];
  __shared__ float bias_tab[32];

  if (tid < 32) bias_tab[tid] = spdE[tid * NHEAD + hh];

#pragma unroll
  for (int jj = 0; jj < 2; jj++) {
    int c = tid + (jj << 8);
    int r = c >> 3, ch = c & 7;
    int4 val = *(const int4*)(qb + ((size_t)(bb * SPAD + qt * 64 + r)) * DMODEL + hh * DHEAD + ch * 8);
    *(int4*)(Qs + r * PST + ch * 8) = val;
  }
  const int tmlb = tml[bb];
  __syncthreads();

  bf16x8 aq[2];
  aq[0] = *(const bf16x8*)(Qs + (w * 16 + l16) * PST + quad * 8);
  aq[1] = *(const bf16x8*)(Qs + (w * 16 + l16) * PST + 32 + quad * 8);

  floatx4 O[4];
  float m_i[4], l_i[4];
#pragma unroll
  for (int d = 0; d < 4; d++) { floatx4 z = {0.f, 0.f, 0.f, 0.f}; O[d] = z; }
#pragma unroll
  for (int r = 0; r < 4; r++) { m_i[r] = -3.0e38f; l_i[r] = 0.f; }

  unsigned short* PsW = Ps + w * 16 * PST;

  for (int kt = 0; kt < 17; kt++) {
#pragma unroll
    for (int jj = 0; jj < 2; jj++) {
      int c = tid + (jj << 8);
      int r = c >> 3, ch = c & 7;
      int4 kv = *(const int4*)(kb + ((size_t)(bb * SPAD + kt * 64 + r)) * DMODEL + hh * DHEAD + ch * 8);
      *(int4*)(Ks + r * PST + ch * 8) = kv;
      int4 vv = *(const int4*)(vt + (((size_t)(bb * NHEAD + hh)) * DHEAD + r) * SPAD + kt * 64 + ch * 8);
      *(int4*)(Vts + r * PST + ch * 8) = vv;
    }
    __syncthreads();

    float sc[4][4];
#pragma unroll
    for (int ns = 0; ns < 4; ns++) {
      bf16x8 bk0 = *(const bf16x8*)(Ks + (ns * 16 + l16) * PST + quad * 8);
      bf16x8 bk1 = *(const bf16x8*)(Ks + (ns * 16 + l16) * PST + 32 + quad * 8);
      floatx4 c4 = {0.f, 0.f, 0.f, 0.f};
      c4 = mfma16(aq[0], bk0, c4);
      c4 = mfma16(aq[1], bk1, c4);
#pragma unroll
      for (int r = 0; r < 4; r++) sc[ns][r] = c4[r];
    }

#pragma unroll
    for (int r = 0; r < 4; r++) {
      int qg = qt * 64 + w * 16 + quad * 4 + r;
      float maskv = (qg < tmlb + 2) ? 0.f : -1.0e9f;
      int qs = (qg >= 2) ? ((qg - 2 < LTOK) ? qg - 2 : LTOK - 1) : 0;
#pragma unroll
      for (int ns = 0; ns < 4; ns++) {
        int kg = kt * 64 + ns * 16 + l16;
        float sv;
        if (kg >= SEQ) {
          sv = -3.0e38f;
        } else {
          int idx;
          if (qg >= 2 && kg >= 2) {
            idx = spd[((size_t)bb * LTOK + qs) * LTOK + (kg - 2)];
            idx = idx < 0 ? 0 : (idx > 31 ? 31 : idx);
          } else {
            idx = (qg == kg) ? 0 : 31;
          }
          sv = sc[ns][r] * 0.125f + bias_tab[idx] + maskv;  // fp32: -1e9 absorbs (ref-faithful)
        }
        sc[ns][r] = sv;
      }
    }

    float alpha[4];
#pragma unroll
    for (int r = 0; r < 4; r++) {
      float mx = fmaxf(fmaxf(sc[0][r], sc[1][r]), fmaxf(sc[2][r], sc[3][r]));
#pragma unroll
      for (int off = 1; off < 16; off <<= 1) mx = fmaxf(mx, __shfl_xor(mx, off));
      float mn = fmaxf(m_i[r], mx);
      alpha[r] = __expf(m_i[r] - mn);
      m_i[r] = mn;
      float rs = 0.f;
#pragma unroll
      for (int ns = 0; ns < 4; ns++) { float p = __expf(sc[ns][r] - mn); sc[ns][r] = p; rs += p; }
#pragma unroll
      for (int off = 1; off < 16; off <<= 1) rs += __shfl_xor(rs, off);
      l_i[r] = l_i[r] * alpha[r] + rs;
    }

#pragma unroll
    for (int ns = 0; ns < 4; ns++)
#pragma unroll
      for (int r = 0; r < 4; r++)
        PsW[(quad * 4 + r) * PST + ns * 16 + l16] = f2b(sc[ns][r]);

#pragma unroll
    for (int d = 0; d < 4; d++)
#pragma unroll
      for (int r = 0; r < 4; r++) O[d][r] *= alpha[r];

    bf16x8 ap0 = *(const bf16x8*)(PsW + l16 * PST + quad * 8);
    bf16x8 ap1 = *(const bf16x8*)(PsW + l16 * PST + 32 + quad * 8);
#pragma unroll
    for (int d = 0; d < 4; d++) {
      bf16x8 bv0 = *(const bf16x8*)(Vts + (d * 16 + l16) * PST + quad * 8);
      bf16x8 bv1 = *(const bf16x8*)(Vts + (d * 16 + l16) * PST + 32 + quad * 8);
      O[d] = mfma16(ap0, bv0, O[d]);
      O[d] = mfma16(ap1, bv1, O[d]);
    }
    __syncthreads();
  }

#pragma unroll
  for (int r = 0; r < 4; r++) {
    int qg = qt * 64 + w * 16 + quad * 4 + r;
    float inv = 1.0f / l_i[r];
#pragma unroll
    for (int d = 0; d < 4; d++)
      attb[((size_t)(bb * SPAD + qg)) * DMODEL + hh * DHEAD + d * 16 + l16] = f2b(O[d][r] * inv);
  }
}

// ---------------- silu(u1) * u3 -> bf16 ----------------
__global__ __launch_bounds__(256) void silumul_kernel(const unsigned short* __restrict__ u,
                                                      unsigned short* __restrict__ g, int n) {
  int i = (blockIdx.x * 256 + threadIdx.x) * 4;
  if (i >= n) return;
  const unsigned short* u3 = u + n;
  ushort4 a = *(const ushort4*)(u + i);
  ushort4 c = *(const ushort4*)(u3 + i);
  ushort4 o;
  float x, y;
  x = b2f(a.x); y = b2f(c.x); o.x = f2b(x / (1.f + __expf(-x)) * y);
  x = b2f(a.y); y = b2f(c.y); o.y = f2b(x / (1.f + __expf(-x)) * y);
  x = b2f(a.z); y = b2f(c.z); o.z = f2b(x / (1.f + __expf(-x)) * y);
  x = b2f(a.w); y = b2f(c.w); o.w = f2b(x / (1.f + __expf(-x)) * y);
  *(ushort4*)(g + i) = o;
}

// ---------------- generic bf16 MFMA GEMM, Bt = (N,K) ----------------
enum { EPI_BF16 = 0, EPI_RESID = 1, EPI_PROJ = 2, EPI_OUT = 3 };

template <int EPI>
__global__ __launch_bounds__(256) void gemm_bt_kernel(
    const unsigned short* __restrict__ A, const unsigned short* __restrict__ Bt,
    void* __restrict__ Cv, const float* __restrict__ bias,
    int M, int N, int K, long zA, long zB, long zC, int Mreal, int Nreal) {
  A += zA * blockIdx.z;
  Bt += zB * blockIdx.z;
  char* Cb = (char*)Cv + zC * blockIdx.z;

  const int tid = threadIdx.x;
  const int lane = tid & 63, wave = tid >> 6;
  const int quad = lane >> 4, l16 = lane & 15;
  const int wr = wave >> 1, wc = wave & 1;
  const int m0 = blockIdx.y << 7, n0 = blockIdx.x << 7;

  __shared__ unsigned short As[128 * 32];
  __shared__ unsigned short Bs[128 * 32];

  floatx4 acc[4][4];
  {
    floatx4 z = {0.f, 0.f, 0.f, 0.f};
#pragma unroll
    for (int i = 0; i < 4; i++)
#pragma unroll
      for (int j = 0; j < 4; j++) acc[i][j] = z;
  }

  for (int k0 = 0; k0 < K; k0 += 32) {
#pragma unroll
    for (int jj = 0; jj < 2; jj++) {
      int c = tid + (jj << 8);
      int r = c >> 2, kc = c & 3;
      gl2lds16(A + (size_t)(m0 + r) * K + k0 + kc * 8, As + c * 8);
      gl2lds16(Bt + (size_t)(n0 + r) * K + k0 + kc * 8, Bs + c * 8);
    }
    __syncthreads();
    bf16x8 a[4], b[4];
#pragma unroll
    for (int i = 0; i < 4; i++) a[i] = *(const bf16x8*)(As + (wr * 64 + i * 16 + l16) * 32 + quad * 8);
#pragma unroll
    for (int j = 0; j < 4; j++) b[j] = *(const bf16x8*)(Bs + (wc * 64 + j * 16 + l16) * 32 + quad * 8);
#pragma unroll
    for (int i = 0; i < 4; i++)
#pragma unroll
      for (int j = 0; j < 4; j++) acc[i][j] = mfma16(a[i], b[j], acc[i][j]);
    __syncthreads();
  }

#pragma unroll
  for (int i = 0; i < 4; i++) {
    const int rb = m0 + wr * 64 + i * 16 + quad * 4;
#pragma unroll
    for (int j = 0; j < 4; j++) {
      const int col = n0 + wc * 64 + j * 16 + l16;
#pragma unroll
      for (int r = 0; r < 4; r++) {
        const int row = rb + r;
        float v = acc[i][j][r];
        if constexpr (EPI == EPI_BF16) {
          ((unsigned short*)Cb)[(size_t)row * N + col] = f2b(v);
        } else if constexpr (EPI == EPI_RESID) {
          float* C = (float*)Cb;
          C[(size_t)row * N + col] += v;
        } else if constexpr (EPI == EPI_PROJ) {
          float* C = (float*)Cb;
          int rr = (row >> 10) * SPAD + 2 + (row & 1023);
          C[(size_t)rr * N + col] = v + bias[col];
        } else {  // EPI_OUT
          if (row < Mreal && col < Nreal)
            ((float*)Cb)[(size_t)row * Nreal + col] = v + bias[col];
        }
      }
    }
  }
}

// ---------------- launcher ----------------
extern "C" void kernel_launch(void* const* d_in, const int* in_sizes, int n_in,
                              void* d_out, int out_size, void* d_ws, size_t ws_size,
                              hipStream_t stream) {
  const float* gf    = (const float*)d_in[0];
  const float* inpf  = (const float*)d_in[1];
  const float* projW = (const float*)d_in[2];
  const float* projB = (const float*)d_in[3];
  const float* sos   = (const float*)d_in[4];
  const float* nodeE = (const float*)d_in[5];
  const float* typeE = (const float*)d_in[6];
  const float* posE  = (const float*)d_in[7];
  const float* spdE  = (const float*)d_in[8];
  const float* attnW = (const float*)d_in[9];
  const float* wq    = (const float*)d_in[10];
  const float* wk    = (const float*)d_in[11];
  const float* wv    = (const float*)d_in[12];
  const float* wo    = (const float*)d_in[13];
  const float* ffnW  = (const float*)d_in[14];
  const float* w1    = (const float*)d_in[15];
  const float* w2    = (const float*)d_in[16];
  const float* w3    = (const float*)d_in[17];
  const float* finW  = (const float*)d_in[18];
  const float* outW  = (const float*)d_in[19];
  const float* outB  = (const float*)d_in[20];
  const int*   sub   = (const int*)d_in[21];
  const int*   tml   = (const int*)d_in[22];
  const int*   spd   = (const int*)d_in[23];
  float* out = (float*)d_out;
  (void)in_sizes; (void)n_in; (void)out_size; (void)ws_size;

  char* ws = (char*)d_ws;
  constexpr size_t OFF_H     = 0;                    // fp32 (MPAD, D)         8,912,896
  constexpr size_t OFF_XB    = 8912896;              // bf16 (MPAD, D)         4,456,448
  constexpr size_t OFF_Q     = 13369344;             // bf16 (MPAD, D)
  constexpr size_t OFF_K     = 17825792;
  constexpr size_t OFF_V     = 22282240;
  constexpr size_t OFF_VT    = 26738688;             // bf16 (B,H,DH,SPAD)
  constexpr size_t OFF_ATT   = 31195136;             // bf16 (MPAD, D)
  constexpr size_t OFF_U     = 35651584;             // bf16 u1,u3 (2x MPAD x DFF)
  constexpr size_t OFF_G     = 71303168;             // bf16 (MPAD, DFF)
  constexpr size_t OFF_XF    = 89128960;             // bf16 (MPAD, D) compact final
  constexpr size_t OFF_INB   = 93585408;             // bf16 (2048, 512)
  constexpr size_t OFF_PROJT = 95682560;             // bf16 (1024, 512)
  constexpr size_t OFF_OUTWT = 96731136;             // bf16 (5120, 1024)
  constexpr size_t OFF_SLAB  = 107216896;            // bf16 per-layer weightsT, 32MB

  float*          h    = (float*)(ws + OFF_H);
  unsigned short* xb   = (unsigned short*)(ws + OFF_XB);
  unsigned short* qbuf = (unsigned short*)(ws + OFF_Q);
  unsigned short* kbuf = (unsigned short*)(ws + OFF_K);
  unsigned short* vbuf = (unsigned short*)(ws + OFF_V);
  unsigned short* vtb  = (unsigned short*)(ws + OFF_VT);
  unsigned short* attb = (unsigned short*)(ws + OFF_ATT);
  unsigned short* ubuf = (unsigned short*)(ws + OFF_U);
  unsigned short* gbuf = (unsigned short*)(ws + OFF_G);
  unsigned short* xf   = (unsigned short*)(ws + OFF_XF);
  unsigned short* inb  = (unsigned short*)(ws + OFF_INB);
  unsigned short* projT = (unsigned short*)(ws + OFF_PROJT);
  unsigned short* outWT = (unsigned short*)(ws + OFF_OUTWT);
  unsigned short* slab  = (unsigned short*)(ws + OFF_SLAB);

  const long DD = (long)DMODEL * DMODEL;          // 1,048,576
  const long DDF = (long)DMODEL * DFF;            // 4,194,304
  const long ZC_TOK = (long)MPAD * DMODEL * 2;    // 4,456,448 bytes
  const long ZC_FF  = (long)MPAD * DFF * 2;       // 17,825,792 bytes

  // ---- one-shot conversions ----
  f2b_kernel<<<1024, 256, 0, stream>>>(inpf, inb, 2048 * 512);
  transconv_kernel<<<dim3(16, 8, 1), 256, 0, stream>>>(projW, projW, projW, projW, projT, 0, 512, 1024);
  transconv_kernel<<<dim3(79, 16, 1), 256, 0, stream>>>(outW, outW, outW, outW, outWT, 0, 1024, NVOC);

  // ---- input projection + h assembly ----
  gemm_bt_kernel<EPI_PROJ><<<dim3(8, 16, 1), 256, 0, stream>>>(
      inb, projT, h, projB, 2048, 1024, 512, 0, 0, 0, 0, 0);
  build_h_kernel<<<dim3(SPAD, 2), 256, 0, stream>>>(h, gf, sos, nodeE, typeE, posE, sub);

  // ---- layers ----
  for (int i = 0; i < 4; i++) {
    transconv_kernel<<<dim3(16, 16, 4), 256, 0, stream>>>(
        wq + (long)i * DD, wk + (long)i * DD, wv + (long)i * DD, wo + (long)i * DD,
        slab, DD, 1024, 1024);
    transconv_kernel<<<dim3(64, 16, 2), 256, 0, stream>>>(
        w1 + (long)i * DDF, w3 + (long)i * DDF, w1, w1,
        slab + 4 * DD, DDF, 1024, 4096);
    transconv_kernel<<<dim3(16, 64, 1), 256, 0, stream>>>(
        w2 + (long)i * DDF, w2, w2, w2,
        slab + 12 * DD, 0, 4096, 1024);

    rmsnorm_kernel<<<MPAD, 256, 0, stream>>>(h, attnW + i * DMODEL, xb, 0);
    gemm_bt_kernel<EPI_BF16><<<dim3(8, 17, 3), 256, 0, stream>>>(
        xb, slab, qbuf, nullptr, MPAD, 1024, 1024, 0, DD, ZC_TOK, 0, 0);
    vtrans_kernel<<<dim3(17, 16, 2), 256, 0, stream>>>(vbuf, vtb);
    attn_kernel<<<dim3(17, 16, 2), 256, 0, stream>>>(qbuf, kbuf, vtb, attb, spdE, spd, tml);
    gemm_bt_kernel<EPI_RESID><<<dim3(8, 17, 1), 256, 0, stream>>>(
        attb, slab + 3 * DD, h, nullptr, MPAD, 1024, 1024, 0, 0, 0, 0, 0);

    rmsnorm_kernel<<<MPAD, 256, 0, stream>>>(h, ffnW + i * DMODEL, xb, 0);
    gemm_bt_kernel<EPI_BF16><<<dim3(32, 17, 2), 256, 0, stream>>>(
        xb, slab + 4 * DD, ubuf, nullptr, MPAD, 4096, 1024, 0, DDF, ZC_FF, 0, 0);
    silumul_kernel<<<8704, 256, 0, stream>>>(ubuf, gbuf, MPAD * DFF);
    gemm_bt_kernel<EPI_RESID><<<dim3(8, 17, 1), 256, 0, stream>>>(
        gbuf, slab + 12 * DD, h, nullptr, MPAD, 1024, 4096, 0, 0, 0, 0, 0);
  }

  // ---- final norm + output projection ----
  rmsnorm_kernel<<<MPAD, 256, 0, stream>>>(h, finW, xf, 1);
  gemm_bt_kernel<EPI_OUT><<<dim3(40, 17, 1), 256, 0, stream>>>(
      xf, outWT, out, outB, MPAD, NVOCP, 1024, 0, 0, 0, MOUT, NVOC);
}

// Round 2
// 1598.039 us; speedup vs baseline: 1.1201x; 1.1201x over previous
//
// PatchedTransformer on MI355X — round 2.
// R1 post-mortem: attn latency-bound on per-head spd int32 gather (70MB HBM fetch/dispatch).
// Changes:
//  1. bidx uint8 precompute (B,SPAD,SPAD)=2.4MB, L2-resident; attn stages 4KB idx tile
//     into LDS with K/V; bias_tab[33] LDS lookup (idx 32 = -3e38 pad mask).
//  2. attn: register prefetch of next K/V/idx tile (global loads in flight during compute).
//  3. wo/w2 GEMMs were 136 blocks (half the CUs idle): split-K w/ fp32 atomicAdd epilogue
//     (wo: 2-way Kc=512 -> 272 blocks; w2: 4-way Kc=1024 -> 544 blocks).
#include <hip/hip_runtime.h>

#define DMODEL 1024
#define DFF    4096
#define NHEAD  16
#define DHEAD  64
#define LTOK   1024
#define SEQ    1026
#define SPAD   1088
#define MPAD   2176
#define NVOC   5000
#define NVOCP  5120
#define MOUT   2050

typedef float  floatx4 __attribute__((ext_vector_type(4)));
typedef __bf16 bf16x8  __attribute__((ext_vector_type(8)));

__device__ __forceinline__ unsigned short f2b(float f) {
  unsigned int u = __builtin_bit_cast(unsigned int, f);
  u += 0x7FFFu + ((u >> 16) & 1u);          // RNE
  return (unsigned short)(u >> 16);
}
__device__ __forceinline__ float b2f(unsigned short v) {
  return __builtin_bit_cast(float, ((unsigned int)v) << 16);
}
__device__ __forceinline__ void gl2lds16(const void* g, void* l) {
  __builtin_amdgcn_global_load_lds((const __attribute__((address_space(1))) void*)g,
                                   (__attribute__((address_space(3))) void*)l, 16, 0, 0);
}
__device__ __forceinline__ floatx4 mfma16(bf16x8 a, bf16x8 b, floatx4 c) {
  return __builtin_amdgcn_mfma_f32_16x16x32_bf16(a, b, c, 0, 0, 0);
}

// ---------------- fp32 -> bf16 flat convert ----------------
__global__ __launch_bounds__(256) void f2b_kernel(const float* __restrict__ s,
                                                  unsigned short* __restrict__ d, int n) {
  int i = (blockIdx.x * 256 + threadIdx.x) * 4;
  if (i >= n) return;
  float4 v = *(const float4*)(s + i);
  ushort4 o; o.x = f2b(v.x); o.y = f2b(v.y); o.z = f2b(v.z); o.w = f2b(v.w);
  *(ushort4*)(d + i) = o;
}

// ------------- fp32 (R,C) -> bf16 transposed (C,R) -------------
__global__ __launch_bounds__(256) void transconv_kernel(
    const float* __restrict__ p0, const float* __restrict__ p1,
    const float* __restrict__ p2, const float* __restrict__ p3,
    unsigned short* __restrict__ dst, long dstZ, int R, int C) {
  const float* src = (blockIdx.z == 0) ? p0 : (blockIdx.z == 1) ? p1 : (blockIdx.z == 2) ? p2 : p3;
  dst += dstZ * blockIdx.z;
  __shared__ float T[64][68];
  const int r0 = blockIdx.y * 64, c0 = blockIdx.x * 64;
  const int tr = threadIdx.x >> 4, tc = threadIdx.x & 15;
#pragma unroll
  for (int it = 0; it < 4; it++) {
    int rl = tr + it * 16;
    int cg = c0 + tc * 4;
    float4 v = {0.f, 0.f, 0.f, 0.f};
    if (cg < C) v = *(const float4*)(src + (size_t)(r0 + rl) * C + cg);
    T[rl][tc * 4 + 0] = v.x; T[rl][tc * 4 + 1] = v.y;
    T[rl][tc * 4 + 2] = v.z; T[rl][tc * 4 + 3] = v.w;
  }
  __syncthreads();
#pragma unroll
  for (int it = 0; it < 4; it++) {
    int ol = tr + it * 16;
    int oc = c0 + ol;
    if (oc < C) {
      ushort4 o;
      o.x = f2b(T[tc * 4 + 0][ol]); o.y = f2b(T[tc * 4 + 1][ol]);
      o.z = f2b(T[tc * 4 + 2][ol]); o.w = f2b(T[tc * 4 + 3][ol]);
      *(ushort4*)(dst + (size_t)oc * R + r0 + tc * 4) = o;
    }
  }
}

// ---------------- embeddings / h assembly ----------------
__global__ __launch_bounds__(256) void build_h_kernel(
    float* __restrict__ h, const float* __restrict__ gf, const float* __restrict__ sos,
    const float* __restrict__ nodeE, const float* __restrict__ typeE,
    const float* __restrict__ posE, const int* __restrict__ sub) {
  const int s = blockIdx.x, b = blockIdx.y;
  const int c = threadIdx.x * 4;
  float* o = h + ((size_t)(b * SPAD + s)) * DMODEL + c;
  if (s >= SEQ) { o[0] = 0.f; o[1] = 0.f; o[2] = 0.f; o[3] = 0.f; return; }
  float4 p = *(const float4*)(posE + (size_t)s * DMODEL + c);
  if (s == 0) {
    float4 g = *(const float4*)(gf + (size_t)b * DMODEL + c);
    float4 t = *(const float4*)(typeE + DMODEL + c);
    o[0] = g.x + t.x + p.x; o[1] = g.y + t.y + p.y;
    o[2] = g.z + t.z + p.z; o[3] = g.w + t.w + p.w;
  } else {
    float4 t = *(const float4*)(typeE + c);
    int nid = (s == 1) ? 0 : sub[b * LTOK + s - 2];
    float4 ne = *(const float4*)(nodeE + (size_t)nid * DMODEL + c);
    if (s == 1) {
      float4 ss = *(const float4*)(sos + c);
      o[0] = ss.x + ne.x + t.x + p.x; o[1] = ss.y + ne.y + t.y + p.y;
      o[2] = ss.z + ne.z + t.z + p.z; o[3] = ss.w + ne.w + t.w + p.w;
    } else {  // adds on top of proj-GEMM output already in h
      o[0] += ne.x + t.x + p.x; o[1] += ne.y + t.y + p.y;
      o[2] += ne.z + t.z + p.z; o[3] += ne.w + t.w + p.w;
    }
  }
}

// ---------------- RMSNorm (fp32 in, bf16 out) ----------------
__global__ __launch_bounds__(256) void rmsnorm_kernel(const float* __restrict__ h,
                                                      const float* __restrict__ w,
                                                      unsigned short* __restrict__ out,
                                                      int final_mode) {
  const int r = blockIdx.x;
  int srow = r;
  if (final_mode) {
    if (r >= MOUT) {
      ushort4 z = {0, 0, 0, 0};
      *(ushort4*)(out + (size_t)r * DMODEL + threadIdx.x * 4) = z;
      return;
    }
    int b = r / 1025;
    srow = b * SPAD + 1 + (r - b * 1025);
  }
  float4 x = *(const float4*)(h + (size_t)srow * DMODEL + threadIdx.x * 4);
  float ss = x.x * x.x + x.y * x.y + x.z * x.z + x.w * x.w;
#pragma unroll
  for (int off = 32; off > 0; off >>= 1) ss += __shfl_down(ss, off);
  __shared__ float red[4];
  if ((threadIdx.x & 63) == 0) red[threadIdx.x >> 6] = ss;
  __syncthreads();
  float rs = rsqrtf((red[0] + red[1] + red[2] + red[3]) * (1.f / 1024.f) + 1e-6f);
  float4 ww = *(const float4*)(w + threadIdx.x * 4);
  ushort4 o;
  o.x = f2b(x.x * rs * ww.x); o.y = f2b(x.y * rs * ww.y);
  o.z = f2b(x.z * rs * ww.z); o.w = f2b(x.w * rs * ww.w);
  *(ushort4*)(out + (size_t)r * DMODEL + threadIdx.x * 4) = o;
}

// ---------------- bias index precompute: uint8 (B, SPAD, SPAD) ----------------
__global__ __launch_bounds__(320) void bidx_kernel(const int* __restrict__ spd,
                                                   unsigned char* __restrict__ bidx) {
  const int qg = blockIdx.x, b = blockIdx.y;
  const int k0 = threadIdx.x * 4;
  if (k0 >= SPAD) return;
  uchar4 o;
  unsigned char v[4];
#pragma unroll
  for (int j = 0; j < 4; j++) {
    int kg = k0 + j;
    if (qg >= SEQ || kg >= SEQ) {
      v[j] = 32;  // padding -> -3e38
    } else if (qg >= 2 && kg >= 2) {
      int idx = spd[((size_t)b * LTOK + (qg - 2)) * LTOK + (kg - 2)];
      v[j] = (unsigned char)(idx < 0 ? 0 : (idx > 31 ? 31 : idx));
    } else {
      v[j] = (qg == kg) ? 0 : 31;
    }
  }
  o.x = v[0]; o.y = v[1]; o.z = v[2]; o.w = v[3];
  *(uchar4*)(bidx + ((size_t)b * SPAD + qg) * SPAD + k0) = o;
}

// ---------------- V transpose: (B,SPAD,D) head slice -> (B,H,DH,SPAD) ----------------
__global__ __launch_bounds__(256) void vtrans_kernel(const unsigned short* __restrict__ v,
                                                     unsigned short* __restrict__ vt) {
  const int st = blockIdx.x, hh = blockIdx.y, b = blockIdx.z;
  __shared__ unsigned short T[64][72];
  const int tr = threadIdx.x >> 4, tc = threadIdx.x & 15;
#pragma unroll
  for (int it = 0; it < 4; it++) {
    int r = tr + it * 16;
    ushort4 val = *(const ushort4*)(v + ((size_t)(b * SPAD + st * 64 + r)) * DMODEL + hh * DHEAD + tc * 4);
    T[r][tc * 4 + 0] = val.x; T[r][tc * 4 + 1] = val.y;
    T[r][tc * 4 + 2] = val.z; T[r][tc * 4 + 3] = val.w;
  }
  __syncthreads();
#pragma unroll
  for (int it = 0; it < 4; it++) {
    int d = tr + it * 16;
    ushort4 o;
    o.x = T[tc * 4 + 0][d]; o.y = T[tc * 4 + 1][d];
    o.z = T[tc * 4 + 2][d]; o.w = T[tc * 4 + 3][d];
    *(ushort4*)(vt + (((size_t)(b * NHEAD + hh)) * DHEAD + d) * SPAD + st * 64 + tc * 4) = o;
  }
}

// ---------------- flash attention w/ LDS bias idx + q-row mask ----------------
#define PST 80  // padded LDS row stride (ushorts)
__global__ __launch_bounds__(256) void attn_kernel(
    const unsigned short* __restrict__ qb, const unsigned short* __restrict__ kb,
    const unsigned short* __restrict__ vt, unsigned short* __restrict__ attb,
    const float* __restrict__ spdE, const unsigned char* __restrict__ bidx,
    const int* __restrict__ tml) {
  const int qt = blockIdx.x, hh = blockIdx.y, bb = blockIdx.z;
  const int tid = threadIdx.x;
  const int w = tid >> 6, lane = tid & 63;
  const int quad = lane >> 4, l16 = lane & 15;

  __shared__ unsigned short Qs[64 * PST];
  __shared__ unsigned short Ks[64 * PST];
  __shared__ unsigned short Vts[64 * PST];
  __shared__ unsigned short Ps[4 * 16 * PST];
  __shared__ unsigned char Is[64 * 64];
  __shared__ float bias_tab[33];

  if (tid < 33) bias_tab[tid] = (tid < 32) ? spdE[tid * NHEAD + hh] : -3.0e38f;

  // stage Q
#pragma unroll
  for (int jj = 0; jj < 2; jj++) {
    int c = tid + (jj << 8);
    int r = c >> 3, ch = c & 7;
    int4 val = *(const int4*)(qb + ((size_t)(bb * SPAD + qt * 64 + r)) * DMODEL + hh * DHEAD + ch * 8);
    *(int4*)(Qs + r * PST + ch * 8) = val;
  }
  const int tmlb = tml[bb];

  // prefetch tile 0 into regs
  const int sr = tid >> 3, sch = tid & 7;          // K/V staging coords (row, chunk)
  const int ir = tid >> 2, ic = (tid & 3) * 16;    // idx staging coords
  int4 kreg[2], vreg[2], ireg;
  {
    const int kt = 0;
#pragma unroll
    for (int jj = 0; jj < 2; jj++) {
      int r = sr + jj * 32;
      kreg[jj] = *(const int4*)(kb + ((size_t)(bb * SPAD + kt * 64 + r)) * DMODEL + hh * DHEAD + sch * 8);
      vreg[jj] = *(const int4*)(vt + (((size_t)(bb * NHEAD + hh)) * DHEAD + r) * SPAD + kt * 64 + sch * 8);
    }
    ireg = *(const int4*)(bidx + ((size_t)bb * SPAD + qt * 64 + ir) * SPAD + kt * 64 + ic);
  }
  __syncthreads();

  bf16x8 aq[2];
  aq[0] = *(const bf16x8*)(Qs + (w * 16 + l16) * PST + quad * 8);
  aq[1] = *(const bf16x8*)(Qs + (w * 16 + l16) * PST + 32 + quad * 8);

  floatx4 O[4];
  float m_i[4], l_i[4];
#pragma unroll
  for (int d = 0; d < 4; d++) { floatx4 z = {0.f, 0.f, 0.f, 0.f}; O[d] = z; }
#pragma unroll
  for (int r = 0; r < 4; r++) { m_i[r] = -3.0e38f; l_i[r] = 0.f; }

  unsigned short* PsW = Ps + w * 16 * PST;
  float maskv[4];
#pragma unroll
  for (int r = 0; r < 4; r++) {
    int qg = qt * 64 + w * 16 + quad * 4 + r;
    maskv[r] = (qg < tmlb + 2) ? 0.f : -1.0e9f;
  }

  for (int kt = 0; kt < 17; kt++) {
    // write prefetched tile to LDS
#pragma unroll
    for (int jj = 0; jj < 2; jj++) {
      int r = sr + jj * 32;
      *(int4*)(Ks + r * PST + sch * 8) = kreg[jj];
      *(int4*)(Vts + r * PST + sch * 8) = vreg[jj];
    }
    *(int4*)(Is + ir * 64 + ic) = ireg;
    __syncthreads();

    // prefetch next tile
    if (kt < 16) {
      const int kn = kt + 1;
#pragma unroll
      for (int jj = 0; jj < 2; jj++) {
        int r = sr + jj * 32;
        kreg[jj] = *(const int4*)(kb + ((size_t)(bb * SPAD + kn * 64 + r)) * DMODEL + hh * DHEAD + sch * 8);
        vreg[jj] = *(const int4*)(vt + (((size_t)(bb * NHEAD + hh)) * DHEAD + r) * SPAD + kn * 64 + sch * 8);
      }
      ireg = *(const int4*)(bidx + ((size_t)bb * SPAD + qt * 64 + ir) * SPAD + kn * 64 + ic);
    }

    float sc[4][4];
#pragma unroll
    for (int ns = 0; ns < 4; ns++) {
      bf16x8 bk0 = *(const bf16x8*)(Ks + (ns * 16 + l16) * PST + quad * 8);
      bf16x8 bk1 = *(const bf16x8*)(Ks + (ns * 16 + l16) * PST + 32 + quad * 8);
      floatx4 c4 = {0.f, 0.f, 0.f, 0.f};
      c4 = mfma16(aq[0], bk0, c4);
      c4 = mfma16(aq[1], bk1, c4);
#pragma unroll
      for (int r = 0; r < 4; r++) sc[ns][r] = c4[r];
    }

#pragma unroll
    for (int r = 0; r < 4; r++) {
      const unsigned char* isrow = Is + (w * 16 + quad * 4 + r) * 64;
#pragma unroll
      for (int ns = 0; ns < 4; ns++) {
        int idx = isrow[ns * 16 + l16];
        sc[ns][r] = sc[ns][r] * 0.125f + bias_tab[idx] + maskv[r];
      }
    }

    float alpha[4];
#pragma unroll
    for (int r = 0; r < 4; r++) {
      float mx = fmaxf(fmaxf(sc[0][r], sc[1][r]), fmaxf(sc[2][r], sc[3][r]));
#pragma unroll
      for (int off = 1; off < 16; off <<= 1) mx = fmaxf(mx, __shfl_xor(mx, off));
      float mn = fmaxf(m_i[r], mx);
      alpha[r] = __expf(m_i[r] - mn);
      m_i[r] = mn;
      float rs = 0.f;
#pragma unroll
      for (int ns = 0; ns < 4; ns++) { float p = __expf(sc[ns][r] - mn); sc[ns][r] = p; rs += p; }
#pragma unroll
      for (int off = 1; off < 16; off <<= 1) rs += __shfl_xor(rs, off);
      l_i[r] = l_i[r] * alpha[r] + rs;
    }

#pragma unroll
    for (int ns = 0; ns < 4; ns++)
#pragma unroll
      for (int r = 0; r < 4; r++)
        PsW[(quad * 4 + r) * PST + ns * 16 + l16] = f2b(sc[ns][r]);

#pragma unroll
    for (int d = 0; d < 4; d++)
#pragma unroll
      for (int r = 0; r < 4; r++) O[d][r] *= alpha[r];

    bf16x8 ap0 = *(const bf16x8*)(PsW + l16 * PST + quad * 8);
    bf16x8 ap1 = *(const bf16x8*)(PsW + l16 * PST + 32 + quad * 8);
#pragma unroll
    for (int d = 0; d < 4; d++) {
      bf16x8 bv0 = *(const bf16x8*)(Vts + (d * 16 + l16) * PST + quad * 8);
      bf16x8 bv1 = *(const bf16x8*)(Vts + (d * 16 + l16) * PST + 32 + quad * 8);
      O[d] = mfma16(ap0, bv0, O[d]);
      O[d] = mfma16(ap1, bv1, O[d]);
    }
    __syncthreads();
  }

#pragma unroll
  for (int r = 0; r < 4; r++) {
    int qg = qt * 64 + w * 16 + quad * 4 + r;
    float inv = 1.0f / l_i[r];
#pragma unroll
    for (int d = 0; d < 4; d++)
      attb[((size_t)(bb * SPAD + qg)) * DMODEL + hh * DHEAD + d * 16 + l16] = f2b(O[d][r] * inv);
  }
}

// ---------------- silu(u1) * u3 -> bf16 ----------------
__global__ __launch_bounds__(256) void silumul_kernel(const unsigned short* __restrict__ u,
                                                      unsigned short* __restrict__ g, int n) {
  int i = (blockIdx.x * 256 + threadIdx.x) * 4;
  if (i >= n) return;
  const unsigned short* u3 = u + n;
  ushort4 a = *(const ushort4*)(u + i);
  ushort4 c = *(const ushort4*)(u3 + i);
  ushort4 o;
  float x, y;
  x = b2f(a.x); y = b2f(c.x); o.x = f2b(x / (1.f + __expf(-x)) * y);
  x = b2f(a.y); y = b2f(c.y); o.y = f2b(x / (1.f + __expf(-x)) * y);
  x = b2f(a.z); y = b2f(c.z); o.z = f2b(x / (1.f + __expf(-x)) * y);
  x = b2f(a.w); y = b2f(c.w); o.w = f2b(x / (1.f + __expf(-x)) * y);
  *(ushort4*)(g + i) = o;
}

// ---------------- generic bf16 MFMA GEMM, Bt = (N,K), ld = row stride ----------------
enum { EPI_BF16 = 0, EPI_RESID = 1, EPI_PROJ = 2, EPI_OUT = 3, EPI_ATOMIC = 4 };

template <int EPI>
__global__ __launch_bounds__(256) void gemm_bt_kernel(
    const unsigned short* __restrict__ A, const unsigned short* __restrict__ Bt,
    void* __restrict__ Cv, const float* __restrict__ bias,
    int M, int N, int K, int ld, long zA, long zB, long zC, int Mreal, int Nreal) {
  A += zA * blockIdx.z;
  Bt += zB * blockIdx.z;
  char* Cb = (char*)Cv + zC * blockIdx.z;

  const int tid = threadIdx.x;
  const int lane = tid & 63, wave = tid >> 6;
  const int quad = lane >> 4, l16 = lane & 15;
  const int wr = wave >> 1, wc = wave & 1;
  const int m0 = blockIdx.y << 7, n0 = blockIdx.x << 7;

  __shared__ unsigned short As[128 * 32];
  __shared__ unsigned short Bs[128 * 32];

  floatx4 acc[4][4];
  {
    floatx4 z = {0.f, 0.f, 0.f, 0.f};
#pragma unroll
    for (int i = 0; i < 4; i++)
#pragma unroll
      for (int j = 0; j < 4; j++) acc[i][j] = z;
  }

  for (int k0 = 0; k0 < K; k0 += 32) {
#pragma unroll
    for (int jj = 0; jj < 2; jj++) {
      int c = tid + (jj << 8);
      int r = c >> 2, kc = c & 3;
      gl2lds16(A + (size_t)(m0 + r) * ld + k0 + kc * 8, As + c * 8);
      gl2lds16(Bt + (size_t)(n0 + r) * ld + k0 + kc * 8, Bs + c * 8);
    }
    __syncthreads();
    bf16x8 a[4], b[4];
#pragma unroll
    for (int i = 0; i < 4; i++) a[i] = *(const bf16x8*)(As + (wr * 64 + i * 16 + l16) * 32 + quad * 8);
#pragma unroll
    for (int j = 0; j < 4; j++) b[j] = *(const bf16x8*)(Bs + (wc * 64 + j * 16 + l16) * 32 + quad * 8);
#pragma unroll
    for (int i = 0; i < 4; i++)
#pragma unroll
      for (int j = 0; j < 4; j++) acc[i][j] = mfma16(a[i], b[j], acc[i][j]);
    __syncthreads();
  }

#pragma unroll
  for (int i = 0; i < 4; i++) {
    const int rb = m0 + wr * 64 + i * 16 + quad * 4;
#pragma unroll
    for (int j = 0; j < 4; j++) {
      const int col = n0 + wc * 64 + j * 16 + l16;
#pragma unroll
      for (int r = 0; r < 4; r++) {
        const int row = rb + r;
        float v = acc[i][j][r];
        if constexpr (EPI == EPI_BF16) {
          ((unsigned short*)Cb)[(size_t)row * N + col] = f2b(v);
        } else if constexpr (EPI == EPI_RESID) {
          float* C = (float*)Cb;
          C[(size_t)row * N + col] += v;
        } else if constexpr (EPI == EPI_PROJ) {
          float* C = (float*)Cb;
          int rr = (row >> 10) * SPAD + 2 + (row & 1023);
          C[(size_t)rr * N + col] = v + bias[col];
        } else if constexpr (EPI == EPI_ATOMIC) {
          atomicAdd(&((float*)Cb)[(size_t)row * N + col], v);
        } else {  // EPI_OUT
          if (row < Mreal && col < Nreal)
            ((float*)Cb)[(size_t)row * Nreal + col] = v + bias[col];
        }
      }
    }
  }
}

// ---------------- launcher ----------------
extern "C" void kernel_launch(void* const* d_in, const int* in_sizes, int n_in,
                              void* d_out, int out_size, void* d_ws, size_t ws_size,
                              hipStream_t stream) {
  const float* gf    = (const float*)d_in[0];
  const float* inpf  = (const float*)d_in[1];
  const float* projW = (const float*)d_in[2];
  const float* projB = (const float*)d_in[3];
  const float* sos   = (const float*)d_in[4];
  const float* nodeE = (const float*)d_in[5];
  const float* typeE = (const float*)d_in[6];
  const float* posE  = (const float*)d_in[7];
  const float* spdE  = (const float*)d_in[8];
  const float* attnW = (const float*)d_in[9];
  const float* wq    = (const float*)d_in[10];
  const float* wk    = (const float*)d_in[11];
  const float* wv    = (const float*)d_in[12];
  const float* wo    = (const float*)d_in[13];
  const float* ffnW  = (const float*)d_in[14];
  const float* w1    = (const float*)d_in[15];
  const float* w2    = (const float*)d_in[16];
  const float* w3    = (const float*)d_in[17];
  const float* finW  = (const float*)d_in[18];
  const float* outW  = (const float*)d_in[19];
  const float* outB  = (const float*)d_in[20];
  const int*   sub   = (const int*)d_in[21];
  const int*   tml   = (const int*)d_in[22];
  const int*   spd   = (const int*)d_in[23];
  float* out = (float*)d_out;
  (void)in_sizes; (void)n_in; (void)out_size; (void)ws_size;

  char* ws = (char*)d_ws;
  constexpr size_t OFF_H     = 0;                    // fp32 (MPAD, D)
  constexpr size_t OFF_XB    = 8912896;              // bf16 (MPAD, D)
  constexpr size_t OFF_Q     = 13369344;             // bf16 (MPAD, D)
  constexpr size_t OFF_K     = 17825792;
  constexpr size_t OFF_V     = 22282240;
  constexpr size_t OFF_VT    = 26738688;             // bf16 (B,H,DH,SPAD)
  constexpr size_t OFF_ATT   = 31195136;             // bf16 (MPAD, D)
  constexpr size_t OFF_U     = 35651584;             // bf16 u1,u3 (2x MPAD x DFF)
  constexpr size_t OFF_G     = 71303168;             // bf16 (MPAD, DFF)
  constexpr size_t OFF_XF    = 89128960;             // bf16 (MPAD, D) final | bidx during layers
  constexpr size_t OFF_INB   = 93585408;             // bf16 (2048, 512)
  constexpr size_t OFF_PROJT = 95682560;             // bf16 (1024, 512)
  constexpr size_t OFF_OUTWT = 96731136;             // bf16 (5120, 1024)
  constexpr size_t OFF_SLAB  = 107216896;            // bf16 per-layer weightsT, 32MB

  float*          h    = (float*)(ws + OFF_H);
  unsigned short* xb   = (unsigned short*)(ws + OFF_XB);
  unsigned short* qbuf = (unsigned short*)(ws + OFF_Q);
  unsigned short* kbuf = (unsigned short*)(ws + OFF_K);
  unsigned short* vbuf = (unsigned short*)(ws + OFF_V);
  unsigned short* vtb  = (unsigned short*)(ws + OFF_VT);
  unsigned short* attb = (unsigned short*)(ws + OFF_ATT);
  unsigned short* ubuf = (unsigned short*)(ws + OFF_U);
  unsigned short* gbuf = (unsigned short*)(ws + OFF_G);
  unsigned short* xf   = (unsigned short*)(ws + OFF_XF);
  unsigned char*  bidx = (unsigned char*)(ws + OFF_XF);   // aliased: bidx live in layers, xf after
  unsigned short* inb  = (unsigned short*)(ws + OFF_INB);
  unsigned short* projT = (unsigned short*)(ws + OFF_PROJT);
  unsigned short* outWT = (unsigned short*)(ws + OFF_OUTWT);
  unsigned short* slab  = (unsigned short*)(ws + OFF_SLAB);

  const long DD = (long)DMODEL * DMODEL;
  const long DDF = (long)DMODEL * DFF;
  const long ZC_TOK = (long)MPAD * DMODEL * 2;
  const long ZC_FF  = (long)MPAD * DFF * 2;

  // ---- one-shot conversions ----
  f2b_kernel<<<1024, 256, 0, stream>>>(inpf, inb, 2048 * 512);
  transconv_kernel<<<dim3(16, 8, 1), 256, 0, stream>>>(projW, projW, projW, projW, projT, 0, 512, 1024);
  transconv_kernel<<<dim3(79, 16, 1), 256, 0, stream>>>(outW, outW, outW, outW, outWT, 0, 1024, NVOC);
  bidx_kernel<<<dim3(SPAD, 2), 320, 0, stream>>>(spd, bidx);

  // ---- input projection + h assembly ----
  gemm_bt_kernel<EPI_PROJ><<<dim3(8, 16, 1), 256, 0, stream>>>(
      inb, projT, h, projB, 2048, 1024, 512, 512, 0, 0, 0, 0, 0);
  build_h_kernel<<<dim3(SPAD, 2), 256, 0, stream>>>(h, gf, sos, nodeE, typeE, posE, sub);

  // ---- layers ----
  for (int i = 0; i < 4; i++) {
    transconv_kernel<<<dim3(16, 16, 4), 256, 0, stream>>>(
        wq + (long)i * DD, wk + (long)i * DD, wv + (long)i * DD, wo + (long)i * DD,
        slab, DD, 1024, 1024);
    transconv_kernel<<<dim3(64, 16, 2), 256, 0, stream>>>(
        w1 + (long)i * DDF, w3 + (long)i * DDF, w1, w1,
        slab + 4 * DD, DDF, 1024, 4096);
    transconv_kernel<<<dim3(16, 64, 1), 256, 0, stream>>>(
        w2 + (long)i * DDF, w2, w2, w2,
        slab + 12 * DD, 0, 4096, 1024);

    rmsnorm_kernel<<<MPAD, 256, 0, stream>>>(h, attnW + i * DMODEL, xb, 0);
    gemm_bt_kernel<EPI_BF16><<<dim3(8, 17, 3), 256, 0, stream>>>(
        xb, slab, qbuf, nullptr, MPAD, 1024, 1024, 1024, 0, DD, ZC_TOK, 0, 0);
    vtrans_kernel<<<dim3(17, 16, 2), 256, 0, stream>>>(vbuf, vtb);
    attn_kernel<<<dim3(17, 16, 2), 256, 0, stream>>>(qbuf, kbuf, vtb, attb, spdE, bidx, tml);
    // wo: split-K 2-way, atomic fp32 residual add -> 272 blocks
    gemm_bt_kernel<EPI_ATOMIC><<<dim3(8, 17, 2), 256, 0, stream>>>(
        attb, slab + 3 * DD, h, nullptr, MPAD, 1024, 512, 1024, 512, 512, 0, 0, 0);

    rmsnorm_kernel<<<MPAD, 256, 0, stream>>>(h, ffnW + i * DMODEL, xb, 0);
    gemm_bt_kernel<EPI_BF16><<<dim3(32, 17, 2), 256, 0, stream>>>(
        xb, slab + 4 * DD, ubuf, nullptr, MPAD, 4096, 1024, 1024, 0, DDF, ZC_FF, 0, 0);
    silumul_kernel<<<8704, 256, 0, stream>>>(ubuf, gbuf, MPAD * DFF);
    // w2: split-K 4-way, atomic fp32 residual add -> 544 blocks
    gemm_bt_kernel<EPI_ATOMIC><<<dim3(8, 17, 4), 256, 0, stream>>>(
        gbuf, slab + 12 * DD, h, nullptr, MPAD, 1024, 1024, 4096, 1024, 1024, 0, 0, 0);
  }

  // ---- final norm + output projection ----
  rmsnorm_kernel<<<MPAD, 256, 0, stream>>>(h, finW, xf, 1);
  gemm_bt_kernel<EPI_OUT><<<dim3(40, 17, 1), 256, 0, stream>>>(
      xf, outWT, out, outB, MPAD, NVOCP, 1024, 1024, 0, 0, 0, MOUT, NVOC);
}

// Round 3
// 1465.773 us; speedup vs baseline: 1.2212x; 1.0902x over previous
//
// PatchedTransformer on MI355X — round 3.
// R2 post-mortem: attn is latency-bound (MfmaUtil 3.7%, VALUBusy 19%, occ 20%, HBM 8%):
// 1.6 blocks/CU gives ~6.4 waves/CU — softmax dep chain unhidden; Is byte-gathers
// tripled LDS bank conflicts.
// Changes:
//  1. attn: 512 threads, 128-q tile -> 288 blocks all co-resident (2 blk/CU, 16 waves/CU).
//  2. bidx stored k-permuted within 64-groups: fixup = 1 ds_read_b32/row (was 16 byte reads).
//  3. attn grid swizzle: blockIdx.x=(h,b) so each XCD reuses ~4 K/V slices (L2 locality).
#include <hip/hip_runtime.h>

#define DMODEL 1024
#define DFF    4096
#define NHEAD  16
#define DHEAD  64
#define LTOK   1024
#define SEQ    1026
#define SPAD   1088
#define MPAD   2176
#define NVOC   5000
#define NVOCP  5120
#define MOUT   2050

typedef float  floatx4 __attribute__((ext_vector_type(4)));
typedef __bf16 bf16x8  __attribute__((ext_vector_type(8)));

__device__ __forceinline__ unsigned short f2b(float f) {
  unsigned int u = __builtin_bit_cast(unsigned int, f);
  u += 0x7FFFu + ((u >> 16) & 1u);          // RNE
  return (unsigned short)(u >> 16);
}
__device__ __forceinline__ float b2f(unsigned short v) {
  return __builtin_bit_cast(float, ((unsigned int)v) << 16);
}
__device__ __forceinline__ void gl2lds16(const void* g, void* l) {
  __builtin_amdgcn_global_load_lds((const __attribute__((address_space(1))) void*)g,
                                   (__attribute__((address_space(3))) void*)l, 16, 0, 0);
}
__device__ __forceinline__ floatx4 mfma16(bf16x8 a, bf16x8 b, floatx4 c) {
  return __builtin_amdgcn_mfma_f32_16x16x32_bf16(a, b, c, 0, 0, 0);
}

// ---------------- fp32 -> bf16 flat convert ----------------
__global__ __launch_bounds__(256) void f2b_kernel(const float* __restrict__ s,
                                                  unsigned short* __restrict__ d, int n) {
  int i = (blockIdx.x * 256 + threadIdx.x) * 4;
  if (i >= n) return;
  float4 v = *(const float4*)(s + i);
  ushort4 o; o.x = f2b(v.x); o.y = f2b(v.y); o.z = f2b(v.z); o.w = f2b(v.w);
  *(ushort4*)(d + i) = o;
}

// ------------- fp32 (R,C) -> bf16 transposed (C,R) -------------
__global__ __launch_bounds__(256) void transconv_kernel(
    const float* __restrict__ p0, const float* __restrict__ p1,
    const float* __restrict__ p2, const float* __restrict__ p3,
    unsigned short* __restrict__ dst, long dstZ, int R, int C) {
  const float* src = (blockIdx.z == 0) ? p0 : (blockIdx.z == 1) ? p1 : (blockIdx.z == 2) ? p2 : p3;
  dst += dstZ * blockIdx.z;
  __shared__ float T[64][68];
  const int r0 = blockIdx.y * 64, c0 = blockIdx.x * 64;
  const int tr = threadIdx.x >> 4, tc = threadIdx.x & 15;
#pragma unroll
  for (int it = 0; it < 4; it++) {
    int rl = tr + it * 16;
    int cg = c0 + tc * 4;
    float4 v = {0.f, 0.f, 0.f, 0.f};
    if (cg < C) v = *(const float4*)(src + (size_t)(r0 + rl) * C + cg);
    T[rl][tc * 4 + 0] = v.x; T[rl][tc * 4 + 1] = v.y;
    T[rl][tc * 4 + 2] = v.z; T[rl][tc * 4 + 3] = v.w;
  }
  __syncthreads();
#pragma unroll
  for (int it = 0; it < 4; it++) {
    int ol = tr + it * 16;
    int oc = c0 + ol;
    if (oc < C) {
      ushort4 o;
      o.x = f2b(T[tc * 4 + 0][ol]); o.y = f2b(T[tc * 4 + 1][ol]);
      o.z = f2b(T[tc * 4 + 2][ol]); o.w = f2b(T[tc * 4 + 3][ol]);
      *(ushort4*)(dst + (size_t)oc * R + r0 + tc * 4) = o;
    }
  }
}

// ---------------- embeddings / h assembly ----------------
__global__ __launch_bounds__(256) void build_h_kernel(
    float* __restrict__ h, const float* __restrict__ gf, const float* __restrict__ sos,
    const float* __restrict__ nodeE, const float* __restrict__ typeE,
    const float* __restrict__ posE, const int* __restrict__ sub) {
  const int s = blockIdx.x, b = blockIdx.y;
  const int c = threadIdx.x * 4;
  float* o = h + ((size_t)(b * SPAD + s)) * DMODEL + c;
  if (s >= SEQ) { o[0] = 0.f; o[1] = 0.f; o[2] = 0.f; o[3] = 0.f; return; }
  float4 p = *(const float4*)(posE + (size_t)s * DMODEL + c);
  if (s == 0) {
    float4 g = *(const float4*)(gf + (size_t)b * DMODEL + c);
    float4 t = *(const float4*)(typeE + DMODEL + c);
    o[0] = g.x + t.x + p.x; o[1] = g.y + t.y + p.y;
    o[2] = g.z + t.z + p.z; o[3] = g.w + t.w + p.w;
  } else {
    float4 t = *(const float4*)(typeE + c);
    int nid = (s == 1) ? 0 : sub[b * LTOK + s - 2];
    float4 ne = *(const float4*)(nodeE + (size_t)nid * DMODEL + c);
    if (s == 1) {
      float4 ss = *(const float4*)(sos + c);
      o[0] = ss.x + ne.x + t.x + p.x; o[1] = ss.y + ne.y + t.y + p.y;
      o[2] = ss.z + ne.z + t.z + p.z; o[3] = ss.w + ne.w + t.w + p.w;
    } else {  // adds on top of proj-GEMM output already in h
      o[0] += ne.x + t.x + p.x; o[1] += ne.y + t.y + p.y;
      o[2] += ne.z + t.z + p.z; o[3] += ne.w + t.w + p.w;
    }
  }
}

// ---------------- RMSNorm (fp32 in, bf16 out) ----------------
__global__ __launch_bounds__(256) void rmsnorm_kernel(const float* __restrict__ h,
                                                      const float* __restrict__ w,
                                                      unsigned short* __restrict__ out,
                                                      int final_mode) {
  const int r = blockIdx.x;
  int srow = r;
  if (final_mode) {
    if (r >= MOUT) {
      ushort4 z = {0, 0, 0, 0};
      *(ushort4*)(out + (size_t)r * DMODEL + threadIdx.x * 4) = z;
      return;
    }
    int b = r / 1025;
    srow = b * SPAD + 1 + (r - b * 1025);
  }
  float4 x = *(const float4*)(h + (size_t)srow * DMODEL + threadIdx.x * 4);
  float ss = x.x * x.x + x.y * x.y + x.z * x.z + x.w * x.w;
#pragma unroll
  for (int off = 32; off > 0; off >>= 1) ss += __shfl_down(ss, off);
  __shared__ float red[4];
  if ((threadIdx.x & 63) == 0) red[threadIdx.x >> 6] = ss;
  __syncthreads();
  float rs = rsqrtf((red[0] + red[1] + red[2] + red[3]) * (1.f / 1024.f) + 1e-6f);
  float4 ww = *(const float4*)(w + threadIdx.x * 4);
  ushort4 o;
  o.x = f2b(x.x * rs * ww.x); o.y = f2b(x.y * rs * ww.y);
  o.z = f2b(x.z * rs * ww.z); o.w = f2b(x.w * rs * ww.w);
  *(ushort4*)(out + (size_t)r * DMODEL + threadIdx.x * 4) = o;
}

// ---------------- bias index precompute: uint8 (B, SPAD, SPAD), k-permuted ----------------
// within each 64-col group: byte (c*4 + n) holds k = g*64 + n*16 + c, so a lane's
// dword at col l16*4 packs idx for ns=0..3 of MFMA column l16.
__global__ __launch_bounds__(320) void bidx_kernel(const int* __restrict__ spd,
                                                   unsigned char* __restrict__ bidx) {
  const int qg = blockIdx.x, b = blockIdx.y;
  const int i0 = threadIdx.x * 4;
  if (i0 >= SPAD) return;
  const int g = i0 >> 6, c = (i0 >> 2) & 15;
  unsigned char v[4];
#pragma unroll
  for (int n = 0; n < 4; n++) {
    int kg = g * 64 + n * 16 + c;
    unsigned char vv;
    if (qg >= SEQ || kg >= SEQ) {
      vv = 32;  // padding -> -3e38
    } else if (qg >= 2 && kg >= 2) {
      int idx = spd[((size_t)b * LTOK + (qg - 2)) * LTOK + (kg - 2)];
      vv = (unsigned char)(idx < 0 ? 0 : (idx > 31 ? 31 : idx));
    } else {
      vv = (qg == kg) ? 0 : 31;
    }
    v[n] = vv;
  }
  uchar4 o; o.x = v[0]; o.y = v[1]; o.z = v[2]; o.w = v[3];
  *(uchar4*)(bidx + ((size_t)b * SPAD + qg) * SPAD + i0) = o;
}

// ---------------- V transpose: (B,SPAD,D) head slice -> (B,H,DH,SPAD) ----------------
__global__ __launch_bounds__(256) void vtrans_kernel(const unsigned short* __restrict__ v,
                                                     unsigned short* __restrict__ vt) {
  const int st = blockIdx.x, hh = blockIdx.y, b = blockIdx.z;
  __shared__ unsigned short T[64][72];
  const int tr = threadIdx.x >> 4, tc = threadIdx.x & 15;
#pragma unroll
  for (int it = 0; it < 4; it++) {
    int r = tr + it * 16;
    ushort4 val = *(const ushort4*)(v + ((size_t)(b * SPAD + st * 64 + r)) * DMODEL + hh * DHEAD + tc * 4);
    T[r][tc * 4 + 0] = val.x; T[r][tc * 4 + 1] = val.y;
    T[r][tc * 4 + 2] = val.z; T[r][tc * 4 + 3] = val.w;
  }
  __syncthreads();
#pragma unroll
  for (int it = 0; it < 4; it++) {
    int d = tr + it * 16;
    ushort4 o;
    o.x = T[tc * 4 + 0][d]; o.y = T[tc * 4 + 1][d];
    o.z = T[tc * 4 + 2][d]; o.w = T[tc * 4 + 3][d];
    *(ushort4*)(vt + (((size_t)(b * NHEAD + hh)) * DHEAD + d) * SPAD + st * 64 + tc * 4) = o;
  }
}

// ---------------- flash attention: 512 thr, 128-q tile, LDS idx dword ----------------
#define PST 80  // padded LDS row stride (ushorts)
__global__ __launch_bounds__(512) void attn_kernel(
    const unsigned short* __restrict__ qb, const unsigned short* __restrict__ kb,
    const unsigned short* __restrict__ vt, unsigned short* __restrict__ attb,
    const float* __restrict__ spdE, const unsigned char* __restrict__ bidx,
    const int* __restrict__ tml) {
  const int hb = blockIdx.x;          // h*2+b : XCD locality swizzle
  const int qt = blockIdx.y;
  const int hh = hb >> 1, bb = hb & 1;
  const int tid = threadIdx.x;
  const int w = tid >> 6, lane = tid & 63;
  const int quad = lane >> 4, l16 = lane & 15;

  __shared__ unsigned short Qs[128 * PST];
  __shared__ unsigned short Ks[64 * PST];
  __shared__ unsigned short Vts[64 * PST];
  __shared__ unsigned short Ps[8 * 16 * PST];
  __shared__ unsigned char Is[128 * 64];
  __shared__ float bias_tab[33];

  if (tid < 33) bias_tab[tid] = (tid < 32) ? spdE[tid * NHEAD + hh] : -3.0e38f;

  // stage Q (row-clamped for qt=8 tail)
#pragma unroll
  for (int jj = 0; jj < 2; jj++) {
    int c = tid + (jj << 9);
    int r = c >> 3, ch = c & 7;
    int qrow = qt * 128 + r; qrow = qrow < SPAD ? qrow : SPAD - 1;
    int4 val = *(const int4*)(qb + ((size_t)(bb * SPAD + qrow)) * DMODEL + hh * DHEAD + ch * 8);
    *(int4*)(Qs + r * PST + ch * 8) = val;
  }
  const int tmlb = tml[bb];

  // prefetch tile 0
  const int sr = tid >> 3, sch = tid & 7;          // K/V staging (row, chunk)
  const int ir = tid >> 2, ic = (tid & 3) * 16;    // idx staging
  const int irow = min(qt * 128 + ir, SPAD - 1);
  int4 kreg, vreg, ireg;
  kreg = *(const int4*)(kb + ((size_t)(bb * SPAD + sr)) * DMODEL + hh * DHEAD + sch * 8);
  vreg = *(const int4*)(vt + (((size_t)(bb * NHEAD + hh)) * DHEAD + sr) * SPAD + sch * 8);
  ireg = *(const int4*)(bidx + ((size_t)bb * SPAD + irow) * SPAD + ic);
  __syncthreads();

  bf16x8 aq[2];
  aq[0] = *(const bf16x8*)(Qs + (w * 16 + l16) * PST + quad * 8);
  aq[1] = *(const bf16x8*)(Qs + (w * 16 + l16) * PST + 32 + quad * 8);

  floatx4 O[4];
  float m_i[4], l_i[4];
#pragma unroll
  for (int d = 0; d < 4; d++) { floatx4 z = {0.f, 0.f, 0.f, 0.f}; O[d] = z; }
#pragma unroll
  for (int r = 0; r < 4; r++) { m_i[r] = -3.0e38f; l_i[r] = 0.f; }

  unsigned short* PsW = Ps + w * 16 * PST;
  float maskv[4];
#pragma unroll
  for (int r = 0; r < 4; r++) {
    int qg = qt * 128 + w * 16 + quad * 4 + r;
    maskv[r] = (qg < tmlb + 2) ? 0.f : -1.0e9f;
  }

  for (int kt = 0; kt < 17; kt++) {
    // write prefetched tile to LDS
    *(int4*)(Ks + sr * PST + sch * 8) = kreg;
    *(int4*)(Vts + sr * PST + sch * 8) = vreg;
    *(int4*)(Is + ir * 64 + ic) = ireg;
    __syncthreads();

    // prefetch next tile
    if (kt < 16) {
      const int kn = kt + 1;
      kreg = *(const int4*)(kb + ((size_t)(bb * SPAD + kn * 64 + sr)) * DMODEL + hh * DHEAD + sch * 8);
      vreg = *(const int4*)(vt + (((size_t)(bb * NHEAD + hh)) * DHEAD + sr) * SPAD + kn * 64 + sch * 8);
      ireg = *(const int4*)(bidx + ((size_t)bb * SPAD + irow) * SPAD + kn * 64 + ic);
    }

    float sc[4][4];
#pragma unroll
    for (int ns = 0; ns < 4; ns++) {
      bf16x8 bk0 = *(const bf16x8*)(Ks + (ns * 16 + l16) * PST + quad * 8);
      bf16x8 bk1 = *(const bf16x8*)(Ks + (ns * 16 + l16) * PST + 32 + quad * 8);
      floatx4 c4 = {0.f, 0.f, 0.f, 0.f};
      c4 = mfma16(aq[0], bk0, c4);
      c4 = mfma16(aq[1], bk1, c4);
#pragma unroll
      for (int r = 0; r < 4; r++) sc[ns][r] = c4[r];
    }

#pragma unroll
    for (int r = 0; r < 4; r++) {
      int row = w * 16 + quad * 4 + r;
      unsigned int iw = *(const unsigned int*)(Is + row * 64 + l16 * 4);
#pragma unroll
      for (int ns = 0; ns < 4; ns++) {
        int idx = (iw >> (8 * ns)) & 0xff;
        sc[ns][r] = sc[ns][r] * 0.125f + bias_tab[idx] + maskv[r];
      }
    }

    float alpha[4];
#pragma unroll
    for (int r = 0; r < 4; r++) {
      float mx = fmaxf(fmaxf(sc[0][r], sc[1][r]), fmaxf(sc[2][r], sc[3][r]));
#pragma unroll
      for (int off = 1; off < 16; off <<= 1) mx = fmaxf(mx, __shfl_xor(mx, off));
      float mn = fmaxf(m_i[r], mx);
      alpha[r] = __expf(m_i[r] - mn);
      m_i[r] = mn;
      float rs = 0.f;
#pragma unroll
      for (int ns = 0; ns < 4; ns++) { float p = __expf(sc[ns][r] - mn); sc[ns][r] = p; rs += p; }
#pragma unroll
      for (int off = 1; off < 16; off <<= 1) rs += __shfl_xor(rs, off);
      l_i[r] = l_i[r] * alpha[r] + rs;
    }

#pragma unroll
    for (int ns = 0; ns < 4; ns++)
#pragma unroll
      for (int r = 0; r < 4; r++)
        PsW[(quad * 4 + r) * PST + ns * 16 + l16] = f2b(sc[ns][r]);

#pragma unroll
    for (int d = 0; d < 4; d++)
#pragma unroll
      for (int r = 0; r < 4; r++) O[d][r] *= alpha[r];

    bf16x8 ap0 = *(const bf16x8*)(PsW + l16 * PST + quad * 8);
    bf16x8 ap1 = *(const bf16x8*)(PsW + l16 * PST + 32 + quad * 8);
#pragma unroll
    for (int d = 0; d < 4; d++) {
      bf16x8 bv0 = *(const bf16x8*)(Vts + (d * 16 + l16) * PST + quad * 8);
      bf16x8 bv1 = *(const bf16x8*)(Vts + (d * 16 + l16) * PST + 32 + quad * 8);
      O[d] = mfma16(ap0, bv0, O[d]);
      O[d] = mfma16(ap1, bv1, O[d]);
    }
    __syncthreads();
  }

#pragma unroll
  for (int r = 0; r < 4; r++) {
    int qg = qt * 128 + w * 16 + quad * 4 + r;
    if (qg < SPAD) {
      float inv = 1.0f / l_i[r];
#pragma unroll
      for (int d = 0; d < 4; d++)
        attb[((size_t)(bb * SPAD + qg)) * DMODEL + hh * DHEAD + d * 16 + l16] = f2b(O[d][r] * inv);
    }
  }
}

// ---------------- silu(u1) * u3 -> bf16 ----------------
__global__ __launch_bounds__(256) void silumul_kernel(const unsigned short* __restrict__ u,
                                                      unsigned short* __restrict__ g, int n) {
  int i = (blockIdx.x * 256 + threadIdx.x) * 4;
  if (i >= n) return;
  const unsigned short* u3 = u + n;
  ushort4 a = *(const ushort4*)(u + i);
  ushort4 c = *(const ushort4*)(u3 + i);
  ushort4 o;
  float x, y;
  x = b2f(a.x); y = b2f(c.x); o.x = f2b(x / (1.f + __expf(-x)) * y);
  x = b2f(a.y); y = b2f(c.y); o.y = f2b(x / (1.f + __expf(-x)) * y);
  x = b2f(a.z); y = b2f(c.z); o.z = f2b(x / (1.f + __expf(-x)) * y);
  x = b2f(a.w); y = b2f(c.w); o.w = f2b(x / (1.f + __expf(-x)) * y);
  *(ushort4*)(g + i) = o;
}

// ---------------- generic bf16 MFMA GEMM, Bt = (N,K), ld = row stride ----------------
enum { EPI_BF16 = 0, EPI_RESID = 1, EPI_PROJ = 2, EPI_OUT = 3, EPI_ATOMIC = 4 };

template <int EPI>
__global__ __launch_bounds__(256) void gemm_bt_kernel(
    const unsigned short* __restrict__ A, const unsigned short* __restrict__ Bt,
    void* __restrict__ Cv, const float* __restrict__ bias,
    int M, int N, int K, int ld, long zA, long zB, long zC, int Mreal, int Nreal) {
  A += zA * blockIdx.z;
  Bt += zB * blockIdx.z;
  char* Cb = (char*)Cv + zC * blockIdx.z;

  const int tid = threadIdx.x;
  const int lane = tid & 63, wave = tid >> 6;
  const int quad = lane >> 4, l16 = lane & 15;
  const int wr = wave >> 1, wc = wave & 1;
  const int m0 = blockIdx.y << 7, n0 = blockIdx.x << 7;

  __shared__ unsigned short As[128 * 32];
  __shared__ unsigned short Bs[128 * 32];

  floatx4 acc[4][4];
  {
    floatx4 z = {0.f, 0.f, 0.f, 0.f};
#pragma unroll
    for (int i = 0; i < 4; i++)
#pragma unroll
      for (int j = 0; j < 4; j++) acc[i][j] = z;
  }

  for (int k0 = 0; k0 < K; k0 += 32) {
#pragma unroll
    for (int jj = 0; jj < 2; jj++) {
      int c = tid + (jj << 8);
      int r = c >> 2, kc = c & 3;
      gl2lds16(A + (size_t)(m0 + r) * ld + k0 + kc * 8, As + c * 8);
      gl2lds16(Bt + (size_t)(n0 + r) * ld + k0 + kc * 8, Bs + c * 8);
    }
    __syncthreads();
    bf16x8 a[4], b[4];
#pragma unroll
    for (int i = 0; i < 4; i++) a[i] = *(const bf16x8*)(As + (wr * 64 + i * 16 + l16) * 32 + quad * 8);
#pragma unroll
    for (int j = 0; j < 4; j++) b[j] = *(const bf16x8*)(Bs + (wc * 64 + j * 16 + l16) * 32 + quad * 8);
#pragma unroll
    for (int i = 0; i < 4; i++)
#pragma unroll
      for (int j = 0; j < 4; j++) acc[i][j] = mfma16(a[i], b[j], acc[i][j]);
    __syncthreads();
  }

#pragma unroll
  for (int i = 0; i < 4; i++) {
    const int rb = m0 + wr * 64 + i * 16 + quad * 4;
#pragma unroll
    for (int j = 0; j < 4; j++) {
      const int col = n0 + wc * 64 + j * 16 + l16;
#pragma unroll
      for (int r = 0; r < 4; r++) {
        const int row = rb + r;
        float v = acc[i][j][r];
        if constexpr (EPI == EPI_BF16) {
          ((unsigned short*)Cb)[(size_t)row * N + col] = f2b(v);
        } else if constexpr (EPI == EPI_RESID) {
          float* C = (float*)Cb;
          C[(size_t)row * N + col] += v;
        } else if constexpr (EPI == EPI_PROJ) {
          float* C = (float*)Cb;
          int rr = (row >> 10) * SPAD + 2 + (row & 1023);
          C[(size_t)rr * N + col] = v + bias[col];
        } else if constexpr (EPI == EPI_ATOMIC) {
          atomicAdd(&((float*)Cb)[(size_t)row * N + col], v);
        } else {  // EPI_OUT
          if (row < Mreal && col < Nreal)
            ((float*)Cb)[(size_t)row * Nreal + col] = v + bias[col];
        }
      }
    }
  }
}

// ---------------- launcher ----------------
extern "C" void kernel_launch(void* const* d_in, const int* in_sizes, int n_in,
                              void* d_out, int out_size, void* d_ws, size_t ws_size,
                              hipStream_t stream) {
  const float* gf    = (const float*)d_in[0];
  const float* inpf  = (const float*)d_in[1];
  const float* projW = (const float*)d_in[2];
  const float* projB = (const float*)d_in[3];
  const float* sos   = (const float*)d_in[4];
  const float* nodeE = (const float*)d_in[5];
  const float* typeE = (const float*)d_in[6];
  const float* posE  = (const float*)d_in[7];
  const float* spdE  = (const float*)d_in[8];
  const float* attnW = (const float*)d_in[9];
  const float* wq    = (const float*)d_in[10];
  const float* wk    = (const float*)d_in[11];
  const float* wv    = (const float*)d_in[12];
  const float* wo    = (const float*)d_in[13];
  const float* ffnW  = (const float*)d_in[14];
  const float* w1    = (const float*)d_in[15];
  const float* w2    = (const float*)d_in[16];
  const float* w3    = (const float*)d_in[17];
  const float* finW  = (const float*)d_in[18];
  const float* outW  = (const float*)d_in[19];
  const float* outB  = (const float*)d_in[20];
  const int*   sub   = (const int*)d_in[21];
  const int*   tml   = (const int*)d_in[22];
  const int*   spd   = (const int*)d_in[23];
  float* out = (float*)d_out;
  (void)in_sizes; (void)n_in; (void)out_size; (void)ws_size;

  char* ws = (char*)d_ws;
  constexpr size_t OFF_H     = 0;                    // fp32 (MPAD, D)
  constexpr size_t OFF_XB    = 8912896;              // bf16 (MPAD, D)
  constexpr size_t OFF_Q     = 13369344;             // bf16 (MPAD, D)
  constexpr size_t OFF_K     = 17825792;
  constexpr size_t OFF_V     = 22282240;
  constexpr size_t OFF_VT    = 26738688;             // bf16 (B,H,DH,SPAD)
  constexpr size_t OFF_ATT   = 31195136;             // bf16 (MPAD, D)
  constexpr size_t OFF_U     = 35651584;             // bf16 u1,u3 (2x MPAD x DFF)
  constexpr size_t OFF_G     = 71303168;             // bf16 (MPAD, DFF)
  constexpr size_t OFF_XF    = 89128960;             // bf16 (MPAD, D) final | bidx during layers
  constexpr size_t OFF_INB   = 93585408;             // bf16 (2048, 512)
  constexpr size_t OFF_PROJT = 95682560;             // bf16 (1024, 512)
  constexpr size_t OFF_OUTWT = 96731136;             // bf16 (5120, 1024)
  constexpr size_t OFF_SLAB  = 107216896;            // bf16 per-layer weightsT, 32MB

  float*          h    = (float*)(ws + OFF_H);
  unsigned short* xb   = (unsigned short*)(ws + OFF_XB);
  unsigned short* qbuf = (unsigned short*)(ws + OFF_Q);
  unsigned short* kbuf = (unsigned short*)(ws + OFF_K);
  unsigned short* vbuf = (unsigned short*)(ws + OFF_V);
  unsigned short* vtb  = (unsigned short*)(ws + OFF_VT);
  unsigned short* attb = (unsigned short*)(ws + OFF_ATT);
  unsigned short* ubuf = (unsigned short*)(ws + OFF_U);
  unsigned short* gbuf = (unsigned short*)(ws + OFF_G);
  unsigned short* xf   = (unsigned short*)(ws + OFF_XF);
  unsigned char*  bidx = (unsigned char*)(ws + OFF_XF);   // aliased: bidx live in layers, xf after
  unsigned short* inb  = (unsigned short*)(ws + OFF_INB);
  unsigned short* projT = (unsigned short*)(ws + OFF_PROJT);
  unsigned short* outWT = (unsigned short*)(ws + OFF_OUTWT);
  unsigned short* slab  = (unsigned short*)(ws + OFF_SLAB);

  const long DD = (long)DMODEL * DMODEL;
  const long DDF = (long)DMODEL * DFF;
  const long ZC_TOK = (long)MPAD * DMODEL * 2;
  const long ZC_FF  = (long)MPAD * DFF * 2;

  // ---- one-shot conversions ----
  f2b_kernel<<<1024, 256, 0, stream>>>(inpf, inb, 2048 * 512);
  transconv_kernel<<<dim3(16, 8, 1), 256, 0, stream>>>(projW, projW, projW, projW, projT, 0, 512, 1024);
  transconv_kernel<<<dim3(79, 16, 1), 256, 0, stream>>>(outW, outW, outW, outW, outWT, 0, 1024, NVOC);
  bidx_kernel<<<dim3(SPAD, 2), 320, 0, stream>>>(spd, bidx);

  // ---- input projection + h assembly ----
  gemm_bt_kernel<EPI_PROJ><<<dim3(8, 16, 1), 256, 0, stream>>>(
      inb, projT, h, projB, 2048, 1024, 512, 512, 0, 0, 0, 0, 0);
  build_h_kernel<<<dim3(SPAD, 2), 256, 0, stream>>>(h, gf, sos, nodeE, typeE, posE, sub);

  // ---- layers ----
  for (int i = 0; i < 4; i++) {
    transconv_kernel<<<dim3(16, 16, 4), 256, 0, stream>>>(
        wq + (long)i * DD, wk + (long)i * DD, wv + (long)i * DD, wo + (long)i * DD,
        slab, DD, 1024, 1024);
    transconv_kernel<<<dim3(64, 16, 2), 256, 0, stream>>>(
        w1 + (long)i * DDF, w3 + (long)i * DDF, w1, w1,
        slab + 4 * DD, DDF, 1024, 4096);
    transconv_kernel<<<dim3(16, 64, 1), 256, 0, stream>>>(
        w2 + (long)i * DDF, w2, w2, w2,
        slab + 12 * DD, 0, 4096, 1024);

    rmsnorm_kernel<<<MPAD, 256, 0, stream>>>(h, attnW + i * DMODEL, xb, 0);
    gemm_bt_kernel<EPI_BF16><<<dim3(8, 17, 3), 256, 0, stream>>>(
        xb, slab, qbuf, nullptr, MPAD, 1024, 1024, 1024, 0, DD, ZC_TOK, 0, 0);
    vtrans_kernel<<<dim3(17, 16, 2), 256, 0, stream>>>(vbuf, vtb);
    attn_kernel<<<dim3(32, 9, 1), 512, 0, stream>>>(qbuf, kbuf, vtb, attb, spdE, bidx, tml);
    // wo: split-K 2-way, atomic fp32 residual add -> 272 blocks
    gemm_bt_kernel<EPI_ATOMIC><<<dim3(8, 17, 2), 256, 0, stream>>>(
        attb, slab + 3 * DD, h, nullptr, MPAD, 1024, 512, 1024, 512, 512, 0, 0, 0);

    rmsnorm_kernel<<<MPAD, 256, 0, stream>>>(h, ffnW + i * DMODEL, xb, 0);
    gemm_bt_kernel<EPI_BF16><<<dim3(32, 17, 2), 256, 0, stream>>>(
        xb, slab + 4 * DD, ubuf, nullptr, MPAD, 4096, 1024, 1024, 0, DDF, ZC_FF, 0, 0);
    silumul_kernel<<<8704, 256, 0, stream>>>(ubuf, gbuf, MPAD * DFF);
    // w2: split-K 4-way, atomic fp32 residual add -> 544 blocks
    gemm_bt_kernel<EPI_ATOMIC><<<dim3(8, 17, 4), 256, 0, stream>>>(
        gbuf, slab + 12 * DD, h, nullptr, MPAD, 1024, 1024, 4096, 1024, 1024, 0, 0, 0);
  }

  // ---- final norm + output projection ----
  rmsnorm_kernel<<<MPAD, 256, 0, stream>>>(h, finW, xf, 1);
  gemm_bt_kernel<EPI_OUT><<<dim3(40, 17, 1), 256, 0, stream>>>(
      xf, outWT, out, outB, MPAD, NVOCP, 1024, 1024, 0, 0, 0, MOUT, NVOC);
}